// Round 1
// 106.262 us; speedup vs baseline: 1.0020x; 1.0020x over previous
//
#include <hip/hip_runtime.h>

#define NM 64
#define NC 10
#define BLOCK 128
#define ROWS 128          // rows per block == threads per block
// ws layout: [0 .. NM*NC) = M[m*NC+c], [NM*NC .. NM*NC+NC) = c0[c]

__global__ __launch_bounds__(128) void cv2d_precompute(
    const float* __restrict__ S,     // [2N,2N] row-major, 2N=128
    const float* __restrict__ d,     // [128]
    const float* __restrict__ bias,  // [64]
    const float* __restrict__ W,     // [10,64]
    const float* __restrict__ bvec,  // [10]
    float* __restrict__ ws)
{
    const int t = blockIdx.x * 128 + threadIdx.x;   // 0..639 over 5 blocks
    const int twoN = 2 * NM;
    if (t < NM * NC) {
        const int m = t / NC;
        const int c = t - m * NC;
        float acc = 0.f;
        #pragma unroll
        for (int k = 0; k < NM; ++k) {
            // A[k][m] = S[2k, 2m];  M[m][c] = sum_k A[k][m] * W[c][k]
            acc += S[(2 * k) * twoN + 2 * m] * W[c * NM + k];
        }
        ws[m * NC + c] = acc;
    }
    if (t < NC) {
        float acc = bvec[t];
        #pragma unroll
        for (int k = 0; k < NM; ++k) {
            acc += (d[2 * k] + bias[k]) * W[t * NM + k];
        }
        ws[NM * NC + t] = acc;
    }
}

__global__ __launch_bounds__(BLOCK) void cv2d_main(
    const float* __restrict__ x,   // [B, 64]
    const float* __restrict__ Mc,  // ws: M[64*10] then c0[10]
    float* __restrict__ out,       // [B, 10]
    int Bn)
{
    // 128 rows x 16 float4 = 32 KB. XOR-swizzled (byte ^= (row&7)<<4) so both
    // the coalesced staging writes and the per-row reads are bank-conflict-free.
    __shared__ float4 tile[ROWS * (NM / 4)];

    const int t = threadIdx.x;
    const int base = blockIdx.x * ROWS;
    const int rows = min(ROWS, Bn - base);       // last block: 64 rows
    const int nf4 = rows * (NM / 4);

    const float4* __restrict__ xg = (const float4*)(x + (size_t)base * NM);

    // Stage: lane-consecutive float4 loads -> fully coalesced (1 KB / wave-load).
    #pragma unroll
    for (int i = 0; i < (ROWS * NM / 4) / BLOCK; ++i) {  // 16 iters
        const int idx = i * BLOCK + t;
        if (idx < nf4) {                          // wave-uniform predicate
            const int r = idx >> 4;               // row within tile
            const int q = idx & 15;               // float4 within row
            tile[(r << 4) | (q ^ (r & 7))] = xg[idx];
        }
    }
    __syncthreads();

    if (t < rows) {
        float acc[NC];
        #pragma unroll
        for (int c = 0; c < NC; ++c) acc[c] = Mc[NM * NC + c];

        #pragma unroll
        for (int q = 0; q < NM / 4; ++q) {
            // Swizzled ds_read_b128: per-octet the (q ^ (t&7)) group index is a
            // permutation of 0..7 -> conflict-free.
            const float4 v = tile[(t << 4) | (q ^ (t & 7))];
            #pragma unroll
            for (int c = 0; c < NC; ++c) {
                // Mc offsets are compile-time constants -> wave-uniform s_load;
                // v_fmac_f32 takes the SGPR operand for free.
                acc[c] += v.x * Mc[(4 * q + 0) * NC + c];
                acc[c] += v.y * Mc[(4 * q + 1) * NC + c];
                acc[c] += v.z * Mc[(4 * q + 2) * NC + c];
                acc[c] += v.w * Mc[(4 * q + 3) * NC + c];
            }
        }

        // 10 floats = 40 B per row: 8-byte aligned always -> float2 stores.
        // Lanes cover a contiguous 2.5 KB span per wave -> lines fully covered.
        float2* __restrict__ o = (float2*)(out + (size_t)(base + t) * NC);
        #pragma unroll
        for (int c = 0; c < NC; c += 2) {
            o[c / 2] = make_float2(acc[c], acc[c + 1]);
        }
    }
}

extern "C" void kernel_launch(void* const* d_in, const int* in_sizes, int n_in,
                              void* d_out, int out_size, void* d_ws, size_t ws_size,
                              hipStream_t stream) {
    const float* x    = (const float*)d_in[0];
    const float* S    = (const float*)d_in[1];
    const float* d    = (const float*)d_in[2];
    const float* bias = (const float*)d_in[3];
    const float* W    = (const float*)d_in[4];
    const float* bvec = (const float*)d_in[5];
    float* out = (float*)d_out;
    float* ws  = (float*)d_ws;

    const int Bn = in_sizes[0] / NM;  // 200000

    cv2d_precompute<<<5, 128, 0, stream>>>(S, d, bias, W, bvec, ws);

    const int grid = (Bn + ROWS - 1) / ROWS;
    cv2d_main<<<grid, BLOCK, 0, stream>>>(x, ws, out, Bn);
}

// Round 2
// 102.897 us; speedup vs baseline: 1.0348x; 1.0327x over previous
//
#include <hip/hip_runtime.h>

#define NM 64
#define NC 10
// ws layout: [0 .. NM*NC) = M[m*NC+c], [NM*NC .. NM*NC+NC) = c0[c]

__global__ __launch_bounds__(128) void cv2d_precompute(
    const float* __restrict__ S,     // [2N,2N] row-major, 2N=128
    const float* __restrict__ d,     // [128]
    const float* __restrict__ bias,  // [64]
    const float* __restrict__ W,     // [10,64]
    const float* __restrict__ bvec,  // [10]
    float* __restrict__ ws)
{
    const int t = blockIdx.x * 128 + threadIdx.x;   // 0..639 over 5 blocks
    const int twoN = 2 * NM;
    if (t < NM * NC) {
        const int m = t / NC;
        const int c = t - m * NC;
        float acc = 0.f;
        #pragma unroll
        for (int k = 0; k < NM; ++k) {
            // A[k][m] = S[2k, 2m];  M[m][c] = sum_k A[k][m] * W[c][k]
            acc += S[(2 * k) * twoN + 2 * m] * W[c * NM + k];
        }
        ws[m * NC + c] = acc;
    }
    if (t < NC) {
        float acc = bvec[t];
        #pragma unroll
        for (int k = 0; k < NM; ++k) {
            acc += (d[2 * k] + bias[k]) * W[t * NM + k];
        }
        ws[NM * NC + t] = acc;
    }
}

__global__ __launch_bounds__(256) void cv2d_main(
    const float* __restrict__ x,   // [B, 64]
    const float* __restrict__ Mc,  // ws: M[64*10] then c0[10]
    float* __restrict__ out,       // [B, 10]
    int Bn)
{
    const int row = blockIdx.x * 256 + threadIdx.x;
    if (row >= Bn) return;

    const float4* __restrict__ xr = (const float4*)(x + (size_t)row * NM);

    // Preload the entire row: 16 independent global_load_dwordx4 in flight
    // (16 KB/wave). Static indices -> registers, not scratch (rule #20: the
    // loop is fully unrolled so every v[q] access is compile-time constant).
    float4 v[NM / 4];
    #pragma unroll
    for (int q = 0; q < NM / 4; ++q) v[q] = xr[q];

    float acc[NC];
    #pragma unroll
    for (int c = 0; c < NC; ++c) acc[c] = Mc[NM * NC + c];

    #pragma unroll
    for (int q = 0; q < NM / 4; ++q) {
        #pragma unroll
        for (int c = 0; c < NC; ++c) {
            // Mc offsets are compile-time constants -> wave-uniform s_load
            // through the constant cache; v_fmac_f32 takes the SGPR operand
            // for free. This is why Mc must stay in global, not LDS.
            acc[c] += v[q].x * Mc[(4 * q + 0) * NC + c];
            acc[c] += v[q].y * Mc[(4 * q + 1) * NC + c];
            acc[c] += v[q].z * Mc[(4 * q + 2) * NC + c];
            acc[c] += v[q].w * Mc[(4 * q + 3) * NC + c];
        }
    }

    // 10 floats = 40 B per row: 8-byte aligned always -> float2 stores.
    float2* __restrict__ o = (float2*)(out + (size_t)row * NC);
    #pragma unroll
    for (int c = 0; c < NC; c += 2) {
        o[c / 2] = make_float2(acc[c], acc[c + 1]);
    }
}

extern "C" void kernel_launch(void* const* d_in, const int* in_sizes, int n_in,
                              void* d_out, int out_size, void* d_ws, size_t ws_size,
                              hipStream_t stream) {
    const float* x    = (const float*)d_in[0];
    const float* S    = (const float*)d_in[1];
    const float* d    = (const float*)d_in[2];
    const float* bias = (const float*)d_in[3];
    const float* W    = (const float*)d_in[4];
    const float* bvec = (const float*)d_in[5];
    float* out = (float*)d_out;
    float* ws  = (float*)d_ws;

    const int Bn = in_sizes[0] / NM;  // 200000

    cv2d_precompute<<<5, 128, 0, stream>>>(S, d, bias, W, bvec, ws);

    const int grid = (Bn + 255) / 256;
    cv2d_main<<<grid, 256, 0, stream>>>(x, ws, out, Bn);
}